// Round 2
// baseline (180.734 us; speedup 1.0000x reference)
//
#include <hip/hip_runtime.h>
#include <math.h>

// 8x8 DCT-II matrix, exact fp32 rounding of the float64 reference values.
static constexpr float Dm[8][8] = {
  { 0.3535533906f, 0.3535533906f, 0.3535533906f, 0.3535533906f, 0.3535533906f, 0.3535533906f, 0.3535533906f, 0.3535533906f},
  { 0.4903926402f, 0.4157348062f, 0.2777851165f, 0.0975451610f,-0.0975451610f,-0.2777851165f,-0.4157348062f,-0.4903926402f},
  { 0.4619397663f, 0.1913417162f,-0.1913417162f,-0.4619397663f,-0.4619397663f,-0.1913417162f, 0.1913417162f, 0.4619397663f},
  { 0.4157348062f,-0.0975451610f,-0.4903926402f,-0.2777851165f, 0.2777851165f, 0.4903926402f, 0.0975451610f,-0.4157348062f},
  { 0.3535533906f,-0.3535533906f,-0.3535533906f, 0.3535533906f, 0.3535533906f,-0.3535533906f,-0.3535533906f, 0.3535533906f},
  { 0.2777851165f,-0.4903926402f, 0.0975451610f, 0.4157348062f,-0.4157348062f,-0.0975451610f, 0.4903926402f,-0.2777851165f},
  { 0.1913417162f,-0.4619397663f, 0.4619397663f,-0.1913417162f,-0.1913417162f, 0.4619397663f,-0.4619397663f, 0.1913417162f},
  { 0.0975451610f,-0.2777851165f, 0.4157348062f,-0.4903926402f, 0.4903926402f,-0.4157348062f, 0.2777851165f,-0.0975451610f},
};

#define PLS 257            // plane row stride (257 % 32 == 1 -> conflict-free)
#define SBS 72             // scratch per-block stride (8 rows * 9)

__global__ __launch_bounds__(256) void jpeg_fused(
    const float* __restrict__ x,
    const float* __restrict__ qlum,
    const float* __restrict__ qchr,
    float* __restrict__ out)
{
  // planes: y, cb, cr for a 256x8 strip. scr: per-8x8-block transpose scratch.
  __shared__ float plane[3][8 * PLS];
  __shared__ float scr[32 * SBS];
  __shared__ float qq[2][64];

  const int t  = threadIdx.x;          // 0..255
  const int wg = blockIdx.x;           // 0..4095
  const int bb = wg >> 5;              // batch index 0..127
  const int br = wg & 31;              // block-row 0..31
  const int base = bb * (3 * 65536) + br * (8 * 256);

  // qs = q / S  (match reference's division by S=1e-5 exactly)
  if (t < 64)            qq[0][t]      = qlum[t]      / 1e-5f;
  else if (t < 128)      qq[1][t - 64] = qchr[t - 64] / 1e-5f;

  // Phase 1: load strip, RGB -> YCbCr into LDS planes (coalesced reads).
  {
    const float* rp = x + base;
    const float* gp = rp + 65536;
    const float* bp = gp + 65536;
#pragma unroll
    for (int k = 0; k < 8; ++k) {
      float r = rp[k * 256 + t];
      float g = gp[k * 256 + t];
      float b = bp[k * 256 + t];
      plane[0][k * PLS + t] =  0.299f   * r + 0.587f    * g + 0.114f    * b;
      plane[1][k * PLS + t] = -0.168736f* r - 0.331264f * g + 0.5f      * b + 128.0f;
      plane[2][k * PLS + t] =  0.5f     * r - 0.418688f * g - 0.081312f * b + 128.0f;
    }
  }
  __syncthreads();

  const int b8 = t >> 3;   // which 8x8 block in the strip (0..31)
  const int r8 = t & 7;    // row (phase A/C) or column (phase B) within block
  const int sb = b8 * SBS;

#pragma unroll 1
  for (int ch = 0; ch < 3; ++ch) {
    // ---- Phase A: row DCT  t1[v][r] = sum_m X[r][m]*D[v][m], store transposed
    {
      float xr[8];
#pragma unroll
      for (int m = 0; m < 8; ++m) xr[m] = plane[ch][r8 * PLS + b8 * 8 + m];
#pragma unroll
      for (int v = 0; v < 8; ++v) {
        float acc = xr[0] * Dm[v][0];
#pragma unroll
        for (int m = 1; m < 8; ++m) acc = fmaf(xr[m], Dm[v][m], acc);
        scr[sb + v * 9 + r8] = acc;   // scr[b][v][row]
      }
    }
    __syncthreads();

    // ---- Phase B: col DCT + quant/dequant + col IDCT (thread owns column v=r8)
    float Z[8];
    {
      float tc[8];
#pragma unroll
      for (int r = 0; r < 8; ++r) tc[r] = scr[sb + r8 * 9 + r];  // t1[v][r]
      const float* qp = qq[(ch == 0) ? 0 : 1];
      float Fv[8];
#pragma unroll
      for (int u = 0; u < 8; ++u) {
        float acc = tc[0] * Dm[u][0];
#pragma unroll
        for (int r = 1; r < 8; ++r) acc = fmaf(tc[r], Dm[u][r], acc);
        float q = qp[u * 8 + r8];            // qs[u][v], broadcast across b8
        Fv[u] = rintf(acc / q) * q;          // round-half-even, IEEE div
      }
#pragma unroll
      for (int m = 0; m < 8; ++m) {
        float acc = Fv[0] * Dm[0][m];
#pragma unroll
        for (int u = 1; u < 8; ++u) acc = fmaf(Fv[u], Dm[u][m], acc);
        Z[m] = acc;                          // Z[m][v] = sum_u D[u][m] F[u][v]
      }
    }
    __syncthreads();                         // all scr reads done before overwrite
#pragma unroll
    for (int m = 0; m < 8; ++m) scr[sb + m * 9 + r8] = Z[m];   // scr[b][m][v]
    __syncthreads();

    // ---- Phase C: row IDCT  Y[r][j] = sum_v Z[r][v]*D[v][j]
    {
      float zr[8];
#pragma unroll
      for (int v = 0; v < 8; ++v) zr[v] = scr[sb + r8 * 9 + v];
#pragma unroll
      for (int j = 0; j < 8; ++j) {
        float acc = zr[0] * Dm[0][j];
#pragma unroll
        for (int v = 1; v < 8; ++v) acc = fmaf(zr[v], Dm[v][j], acc);
        plane[ch][r8 * PLS + b8 * 8 + j] = acc;
      }
    }
    __syncthreads();   // scr reads done before next channel's A; plane visible
  }

  // Phase 2: YCbCr -> RGB, clip, coalesced stores.
  {
    float* orp = out + base;
    float* ogp = orp + 65536;
    float* obp = ogp + 65536;
#pragma unroll
    for (int k = 0; k < 8; ++k) {
      float y  = plane[0][k * PLS + t];
      float cb = plane[1][k * PLS + t] - 128.0f;
      float cr = plane[2][k * PLS + t] - 128.0f;
      float r2 = fmaf( 1.402f, cr, y);
      float g2 = y - 0.344136f * cb - 0.714136f * cr;
      float b2 = fmaf( 1.722f, cb, y);
      orp[k * 256 + t] = fminf(fmaxf(r2, 0.0f), 255.0f);
      ogp[k * 256 + t] = fminf(fmaxf(g2, 0.0f), 255.0f);
      obp[k * 256 + t] = fminf(fmaxf(b2, 0.0f), 255.0f);
    }
  }
}

extern "C" void kernel_launch(void* const* d_in, const int* in_sizes, int n_in,
                              void* d_out, int out_size, void* d_ws, size_t ws_size,
                              hipStream_t stream) {
  (void)in_sizes; (void)n_in; (void)out_size; (void)d_ws; (void)ws_size;
  const float* x    = (const float*)d_in[0];
  const float* qlum = (const float*)d_in[1];
  const float* qchr = (const float*)d_in[2];
  float* out = (float*)d_out;
  // 128 batches * 32 block-rows = 4096 workgroups of 256 threads.
  jpeg_fused<<<dim3(4096), dim3(256), 0, stream>>>(x, qlum, qchr, out);
}